// Round 5
// baseline (343.344 us; speedup 1.0000x reference)
//
#include <hip/hip_runtime.h>

typedef unsigned short u16;
typedef __attribute__((ext_vector_type(8))) short s8v;
typedef __attribute__((ext_vector_type(4))) float f4v;

enum { MODE_PLAIN = 0, MODE_QKV = 1, MODE_SCALE = 2, MODE_FINAL = 3, MODE_PV = 4 };

__device__ __forceinline__ u16 f2bf(float f) {
  unsigned u = __builtin_bit_cast(unsigned, f);
  u += 0x7fffu + ((u >> 16) & 1u);
  return (u16)(u >> 16);
}
__device__ __forceinline__ float bf2f(u16 h) {
  unsigned u = ((unsigned)h) << 16;
  return __builtin_bit_cast(float, u);
}
__device__ __forceinline__ void gload16(const void* g, void* l) {
  __builtin_amdgcn_global_load_lds(
      (const __attribute__((address_space(1))) unsigned int*)g,
      (__attribute__((address_space(3))) unsigned int*)l, 16, 0, 0);
}

// ---------------- weight fp32 -> bf16 ----------------
__global__ __launch_bounds__(256) void w2bf(const float* __restrict__ w0,
                                            const float* __restrict__ w1,
                                            const float* __restrict__ w2,
                                            const float* __restrict__ w3,
                                            u16* __restrict__ out) {
  int which = blockIdx.y;
  const float* w = which == 0 ? w0 : which == 1 ? w1 : which == 2 ? w2 : w3;
  int i = (blockIdx.x * 256 + threadIdx.x) * 4;
  float4 f = *(const float4*)(w + i);
  u16* o = out + (long)which * 262144 + i;
  ushort4 r;
  r.x = f2bf(f.x); r.y = f2bf(f.y); r.z = f2bf(f.z); r.w = f2bf(f.w);
  *(ushort4*)o = r;
}

// ---------------- groupnorm: partial stats ----------------
__global__ __launch_bounds__(256) void gn_stats(const float* __restrict__ x,
                                                float2* __restrict__ part) {
  const int bid = blockIdx.x;
  const float4* p4 = (const float4*)(x + (long)bid * 8192);
  float s = 0.f, q = 0.f;
  int t = threadIdx.x;
#pragma unroll
  for (int j = 0; j < 8; ++j) {
    float4 f = p4[t + 256 * j];
    s += f.x + f.y + f.z + f.w;
    q += f.x * f.x + f.y * f.y + f.z * f.z + f.w * f.w;
  }
#pragma unroll
  for (int o = 32; o; o >>= 1) {
    s += __shfl_xor(s, o, 64);
    q += __shfl_xor(q, o, 64);
  }
  __shared__ float rs[4], rq[4];
  int lane = t & 63, wv = t >> 6;
  if (lane == 0) { rs[wv] = s; rq[wv] = q; }
  __syncthreads();
  if (t == 0)
    part[bid] = make_float2(rs[0] + rs[1] + rs[2] + rs[3],
                            rq[0] + rq[1] + rq[2] + rq[3]);
}

// ---------------- groupnorm: per-channel scale/shift ----------------
__global__ __launch_bounds__(256) void gn_ab(const float2* __restrict__ part,
                                             const float* __restrict__ gamma,
                                             const float* __restrict__ beta,
                                             float2* __restrict__ AB) {
  int idx = blockIdx.x * 256 + threadIdx.x;
  int g = idx >> 4;
  float s = 0.f, q = 0.f;
#pragma unroll
  for (int j = 0; j < 8; ++j) {
    float2 pp = part[g * 8 + j];
    s += pp.x; q += pp.y;
  }
  float mean = s * (1.0f / 65536.0f);
  float var = q * (1.0f / 65536.0f) - mean * mean;
  int c = idx & 511;
  float a = gamma[c] * rsqrtf(var + 1e-6f);
  AB[idx] = make_float2(a, beta[c] - mean * a);
}

// ---------------- apply groupnorm + transpose ----------------
__global__ __launch_bounds__(256) void gn_apply_t(const float* __restrict__ x,
                                                  const float2* __restrict__ AB,
                                                  u16* __restrict__ hnt) {
  int p0 = blockIdx.x * 32, c0 = blockIdx.y * 32, b = blockIdx.z;
  __shared__ float tile[32][33];
  int t = threadIdx.x;
  const float* xb = x + (long)b * 2097152;
#pragma unroll
  for (int j = 0; j < 4; ++j) {
    int lc = (t >> 5) + j * 8, lp = t & 31;
    tile[lc][lp] = xb[(long)(c0 + lc) * 4096 + p0 + lp];
  }
  __syncthreads();
#pragma unroll
  for (int j = 0; j < 4; ++j) {
    int lp = (t >> 5) + j * 8, lc = t & 31;
    float2 ab = AB[b * 512 + c0 + lc];
    float val = tile[lc][lp] * ab.x + ab.y;
    hnt[(long)b * 2097152 + (long)(p0 + lp) * 512 + c0 + lc] = f2bf(val);
  }
}

// ---------------- in-place row softmax on bf16 [8192][4096] ----------------
__global__ __launch_bounds__(256) void softmax_rows(u16* __restrict__ S) {
  u16* p = S + (long)blockIdx.x * 4096;
  const int t = threadIdx.x;
  s8v h0 = ((const s8v*)p)[t * 2];
  s8v h1 = ((const s8v*)p)[t * 2 + 1];
  float v[16];
#pragma unroll
  for (int j = 0; j < 8; ++j) {
    v[j] = bf2f((u16)h0[j]);
    v[8 + j] = bf2f((u16)h1[j]);
  }
  float mx = v[0];
#pragma unroll
  for (int j = 1; j < 16; ++j) mx = fmaxf(mx, v[j]);
#pragma unroll
  for (int o = 32; o; o >>= 1) mx = fmaxf(mx, __shfl_xor(mx, o, 64));
  __shared__ float red[4], red2[4];
  int lane = t & 63, wv = t >> 6;
  if (lane == 0) red[wv] = mx;
  __syncthreads();
  mx = fmaxf(fmaxf(red[0], red[1]), fmaxf(red[2], red[3]));
  float s = 0.f;
#pragma unroll
  for (int j = 0; j < 16; ++j) {
    v[j] = __expf(v[j] - mx);
    s += v[j];
  }
#pragma unroll
  for (int o = 32; o; o >>= 1) s += __shfl_xor(s, o, 64);
  if (lane == 0) red2[wv] = s;
  __syncthreads();
  s = red2[0] + red2[1] + red2[2] + red2[3];
  float inv = 1.0f / s;
  s8v o0, o1;
#pragma unroll
  for (int j = 0; j < 8; ++j) {
    o0[j] = (short)f2bf(v[j] * inv);
    o1[j] = (short)f2bf(v[8 + j] * inv);
  }
  ((s8v*)p)[t * 2] = o0;
  ((s8v*)p)[t * 2 + 1] = o1;
}

// ---------------- split-K reduce: out = p[i] + p[4194304+i] (bf16) ---------
__global__ __launch_bounds__(256) void reduce_pv(const u16* __restrict__ p,
                                                 u16* __restrict__ out) {
  long i = ((long)blockIdx.x * 256 + threadIdx.x) * 8;
  s8v a = *(const s8v*)(p + i);
  s8v b = *(const s8v*)(p + 4194304 + i);
  s8v o;
#pragma unroll
  for (int j = 0; j < 8; ++j)
    o[j] = (short)f2bf(bf2f((u16)a[j]) + bf2f((u16)b[j]));
  *(s8v*)(out + i) = o;
}

// ---------------- NT GEMM: C[M][N] = A[M][K] * Bt[N][K]^T ----------------
// 3-stage software pipeline (AITER-style): 3 LDS buffers, fine-grained
// s_waitcnt vmcnt(NLD) (never 0 mid-loop), ONE raw s_barrier per K-step,
// loads stay in flight across the barrier. XCD-aware swizzle.
template <int MODE, int BM, int BN>
__global__ __launch_bounds__(256) void gemm_nt(
    const u16* __restrict__ Ag, long sA, const u16* __restrict__ Btg, long sB,
    void* __restrict__ Cg, long sC, int nx, int nyg, int K, long lda, long ldb,
    int N, const float* __restrict__ b0, const float* __restrict__ b1,
    const float* __restrict__ b2, const float* __restrict__ resid, long sR,
    u16* __restrict__ Cv, float scale) {
  constexpr int MI = BM / 32, NI = BN / 32;
  constexpr int AGW = BM / 64, BGW = BN / 64;  // gload16 issues per thread/stage
  constexpr int NLD = AGW + BGW;
  __shared__ __align__(16) u16 lds_a[3][BM * 32];
  __shared__ __align__(16) u16 lds_b[3][BN * 32];
  const int t = threadIdx.x;
  const int lane = t & 63, wv = t >> 6;
  const int wm = wv >> 1, wn = wv & 1;

  int lin = blockIdx.x;
  int xcd = lin & 7, s = lin >> 3;
  int bn_i = s % nx, t2 = s / nx;
  int bm_i = (t2 % nyg) * 8 + xcd;
  int bz = t2 / nyg;

  const u16* A = Ag;
  const u16* Bt = Btg;
  const float* bias = b0;
  long c_off = 0;
  int w_idx = 0, bb = 0;
  if constexpr (MODE == MODE_QKV) {
    w_idx = bz >> 1; bb = bz & 1;
    A += (long)bb * sA;
    Bt += (long)w_idx * 262144;
    c_off = (long)w_idx * 4194304 + (long)bb * sC;
    bias = (w_idx == 0) ? b0 : (w_idx == 1) ? b1 : b2;
  } else if constexpr (MODE == MODE_PV) {
    int ks = bz >> 1; bb = bz & 1;
    A += (long)bb * sA + (long)ks * 2048;
    Bt += (long)bb * sB + (long)ks * 2048;
    c_off = (long)ks * 4194304 + (long)bb * sC;
  } else {
    A += (long)bz * sA;
    Bt += (long)bz * sB;
    c_off = (long)bz * sC;
  }
  const int bm = bm_i * BM, bn = bn_i * BN;

  const u16* aP[AGW];
  const u16* bP[BGW];
#pragma unroll
  for (int j = 0; j < AGW; ++j)
    aP[j] = A + (long)(bm + (wv + j * 4) * 16 + (lane & 15)) * lda +
            (lane >> 4) * 8;
#pragma unroll
  for (int j = 0; j < BGW; ++j)
    bP[j] = Bt + (long)(bn + (wv + j * 4) * 16 + (lane & 15)) * ldb +
            (lane >> 4) * 8;

  auto issue = [&](int buf) {
#pragma unroll
    for (int j = 0; j < AGW; ++j) {
      gload16(aP[j], &lds_a[buf][(wv + j * 4) * 512 + lane * 8]);
      aP[j] += 32;
    }
#pragma unroll
    for (int j = 0; j < BGW; ++j) {
      gload16(bP[j], &lds_b[buf][(wv + j * 4) * 512 + lane * 8]);
      bP[j] += 32;
    }
  };

  f4v acc[MI][NI];
#pragma unroll
  for (int i = 0; i < MI; ++i)
#pragma unroll
    for (int j = 0; j < NI; ++j) acc[i][j] = (f4v){0.f, 0.f, 0.f, 0.f};

  const int NIT = K / 32;
  issue(0);
  if (NIT > 1) issue(1);

  int cur = 0, nxt = 2;
  for (int it = 0; it < NIT; ++it) {
    // wait only the OLDEST stage's loads (vmcnt counts in issue order);
    // stage it+1's loads stay in flight across the barrier.
    if (it < NIT - 1)
      asm volatile("s_waitcnt vmcnt(%0)" ::"n"(NLD) : "memory");
    else
      asm volatile("s_waitcnt vmcnt(0)" ::: "memory");
    asm volatile("s_barrier" ::: "memory");
    // all waves finished compute(it-1); safe to overwrite buf[(it+2)%3]
    if (it + 2 < NIT) issue(nxt);

    s8v af[MI], bfr[NI];
#pragma unroll
    for (int mi = 0; mi < MI; ++mi)
      af[mi] = *(const s8v*)&lds_a[cur][((wm * MI + mi) * 64 + lane) * 8];
#pragma unroll
    for (int ni = 0; ni < NI; ++ni)
      bfr[ni] = *(const s8v*)&lds_b[cur][((wn * NI + ni) * 64 + lane) * 8];
#pragma unroll
    for (int mi = 0; mi < MI; ++mi)
#pragma unroll
      for (int ni = 0; ni < NI; ++ni)
        acc[mi][ni] = __builtin_amdgcn_mfma_f32_16x16x32_bf16(
            af[mi], bfr[ni], acc[mi][ni], 0, 0, 0);
    cur = cur == 2 ? 0 : cur + 1;
    nxt = nxt == 2 ? 0 : nxt + 1;
  }

  const int quad = lane >> 4, col = lane & 15;
#pragma unroll
  for (int mi = 0; mi < MI; ++mi) {
#pragma unroll
    for (int ni = 0; ni < NI; ++ni) {
      int n = bn + wn * (BN / 2) + ni * 16 + col;
      int m0 = bm + wm * (BM / 2) + mi * 16 + quad * 4;
      f4v vv = acc[mi][ni];
      if constexpr (MODE == MODE_QKV) {
        if (w_idx == 2) {
          // v output: [b][c=n][p=m], 4 consecutive m -> packed 8B store
          float bsv = bias[n];
          ushort4 pk;
          pk.x = f2bf(vv[0] + bsv); pk.y = f2bf(vv[1] + bsv);
          pk.z = f2bf(vv[2] + bsv); pk.w = f2bf(vv[3] + bsv);
          *(ushort4*)&Cv[(long)bb * 2097152 + (long)n * 4096 + m0] = pk;
          continue;
        }
      }
#pragma unroll
      for (int r2 = 0; r2 < 4; ++r2) {
        int m = m0 + r2;
        float val = vv[r2];
        if constexpr (MODE == MODE_SCALE) val *= scale;
        if constexpr (MODE == MODE_QKV) val += bias[n];
        if constexpr (MODE == MODE_FINAL) {
          val += b0[m] + resid[(long)bz * sR + (long)m * N + n];
          ((float*)Cg)[c_off + (long)m * N + n] = val;
        } else {
          ((u16*)Cg)[c_off + (long)m * N + n] = f2bf(val);
        }
      }
    }
  }
  (void)scale; (void)bias; (void)resid; (void)Cv;
}

extern "C" void kernel_launch(void* const* d_in, const int* in_sizes, int n_in,
                              void* d_out, int out_size, void* d_ws,
                              size_t ws_size, hipStream_t stream) {
  const float* x = (const float*)d_in[0];
  const float* gamma = (const float*)d_in[1];
  const float* beta = (const float*)d_in[2];
  const float* wq = (const float*)d_in[3];
  const float* bq = (const float*)d_in[4];
  const float* wk = (const float*)d_in[5];
  const float* bk = (const float*)d_in[6];
  const float* wv = (const float*)d_in[7];
  const float* bv = (const float*)d_in[8];
  const float* wo = (const float*)d_in[9];
  const float* bo = (const float*)d_in[10];

  u16* ws = (u16*)d_ws;
  u16* hnt = ws;            // [2][4096][512]; after QKV free; reduce -> out_t
  u16* qt = ws + 4194304;   // q_t; during PV: split-K partial ks=0
  u16* kt = ws + 8388608;   // k_t; during PV: split-K partial ks=1
  u16* vt = ws + 12582912;  // v [2][512][4096] (written transposed by QKV)
  u16* S = ws + 16777216;   // [2][4096][4096] bf16
  u16* wqb = ws + 50331648; // 4 weights bf16
  u16* wob = ws + 51118080;
  float2* part = (float2*)((char*)d_ws + 102760448);
  float2* AB = (float2*)((char*)d_ws + 102764544);

  w2bf<<<dim3(256, 4), 256, 0, stream>>>(wq, wk, wv, wo, wqb);
  gn_stats<<<512, 256, 0, stream>>>(x, part);
  gn_ab<<<4, 256, 0, stream>>>(part, gamma, beta, AB);
  gn_apply_t<<<dim3(128, 16, 2), 256, 0, stream>>>(x, AB, hnt);

  // q_t/k_t [p][co] + v [c][p]: nx=8, nyg=4, nz=6 -> 1536 blocks
  gemm_nt<MODE_QKV, 128, 64><<<1536, 256, 0, stream>>>(
      hnt, 2097152, wqb, 0, qt, 2097152, 8, 4, 512, 512, 512, 512, bq, bk, bv,
      nullptr, 0, vt, 0.f);

  // S = scale * q_t k_t^T: nx=32, nyg=4, nz=2 -> 2048 blocks
  gemm_nt<MODE_SCALE, 128, 128><<<2048, 256, 0, stream>>>(
      qt, 2097152, kt, 2097152, S, 16777216L, 32, 4, 512, 512, 512, 4096,
      nullptr, nullptr, nullptr, nullptr, 0, nullptr, 0.044194173824159216f);

  softmax_rows<<<8192, 256, 0, stream>>>(S);

  // PV split-K=2, 128x64 tiles: nx=8, nyg=4, nz=4 -> 1024 blocks
  gemm_nt<MODE_PV, 128, 64><<<1024, 256, 0, stream>>>(
      S, 16777216L, vt, 2097152, qt, 2097152, 8, 4, 2048, 4096, 4096, 512,
      nullptr, nullptr, nullptr, nullptr, 0, nullptr, 0.f);

  // out_t = partial0 + partial1 -> hnt slot
  reduce_pv<<<2048, 256, 0, stream>>>(qt, hnt);

  // d_out = wo . out_t^T + bo + x: 64x64 tiles, nx=64, nyg=1, nz=2 -> 1024
  gemm_nt<MODE_FINAL, 64, 64><<<1024, 256, 0, stream>>>(
      wob, 0, hnt, 2097152, d_out, 2097152, 64, 1, 512, 512, 512, 4096, bo,
      nullptr, nullptr, x, 2097152, nullptr, 0.f);

  (void)in_sizes; (void)n_in; (void)out_size; (void)ws_size;
}

// Round 6
// 303.086 us; speedup vs baseline: 1.1328x; 1.1328x over previous
//
#include <hip/hip_runtime.h>

typedef unsigned short u16;
typedef __attribute__((ext_vector_type(8))) short s8v;
typedef __attribute__((ext_vector_type(4))) float f4v;

enum { MODE_PLAIN = 0, MODE_SCALE = 2, MODE_FINAL = 3, MODE_PV = 4 };

__device__ __forceinline__ u16 f2bf(float f) {
  unsigned u = __builtin_bit_cast(unsigned, f);
  u += 0x7fffu + ((u >> 16) & 1u);
  return (u16)(u >> 16);
}
__device__ __forceinline__ float bf2f(u16 h) {
  unsigned u = ((unsigned)h) << 16;
  return __builtin_bit_cast(float, u);
}
__device__ __forceinline__ void gload16(const void* g, void* l) {
  __builtin_amdgcn_global_load_lds(
      (const __attribute__((address_space(1))) unsigned int*)g,
      (__attribute__((address_space(3))) unsigned int*)l, 16, 0, 0);
}

// ---------------- weight fp32 -> bf16 ----------------
__global__ __launch_bounds__(256) void w2bf(const float* __restrict__ w0,
                                            const float* __restrict__ w1,
                                            const float* __restrict__ w2,
                                            const float* __restrict__ w3,
                                            u16* __restrict__ out) {
  int which = blockIdx.y;
  const float* w = which == 0 ? w0 : which == 1 ? w1 : which == 2 ? w2 : w3;
  int i = (blockIdx.x * 256 + threadIdx.x) * 4;
  float4 f = *(const float4*)(w + i);
  u16* o = out + (long)which * 262144 + i;
  ushort4 r;
  r.x = f2bf(f.x); r.y = f2bf(f.y); r.z = f2bf(f.z); r.w = f2bf(f.w);
  *(ushort4*)o = r;
}

// ---------------- groupnorm: partial stats ----------------
__global__ __launch_bounds__(256) void gn_stats(const float* __restrict__ x,
                                                float2* __restrict__ part) {
  const int bid = blockIdx.x;
  const float4* p4 = (const float4*)(x + (long)bid * 8192);
  float s = 0.f, q = 0.f;
  int t = threadIdx.x;
#pragma unroll
  for (int j = 0; j < 8; ++j) {
    float4 f = p4[t + 256 * j];
    s += f.x + f.y + f.z + f.w;
    q += f.x * f.x + f.y * f.y + f.z * f.z + f.w * f.w;
  }
#pragma unroll
  for (int o = 32; o; o >>= 1) {
    s += __shfl_xor(s, o, 64);
    q += __shfl_xor(q, o, 64);
  }
  __shared__ float rs[4], rq[4];
  int lane = t & 63, wv = t >> 6;
  if (lane == 0) { rs[wv] = s; rq[wv] = q; }
  __syncthreads();
  if (t == 0)
    part[bid] = make_float2(rs[0] + rs[1] + rs[2] + rs[3],
                            rq[0] + rq[1] + rq[2] + rq[3]);
}

// ---------------- groupnorm: per-channel scale/shift ----------------
__global__ __launch_bounds__(256) void gn_ab(const float2* __restrict__ part,
                                             const float* __restrict__ gamma,
                                             const float* __restrict__ beta,
                                             float2* __restrict__ AB) {
  int idx = blockIdx.x * 256 + threadIdx.x;
  int g = idx >> 4;
  float s = 0.f, q = 0.f;
#pragma unroll
  for (int j = 0; j < 8; ++j) {
    float2 pp = part[g * 8 + j];
    s += pp.x; q += pp.y;
  }
  float mean = s * (1.0f / 65536.0f);
  float var = q * (1.0f / 65536.0f) - mean * mean;
  int c = idx & 511;
  float a = gamma[c] * rsqrtf(var + 1e-6f);
  AB[idx] = make_float2(a, beta[c] - mean * a);
}

// ---------------- apply groupnorm + transpose ----------------
__global__ __launch_bounds__(256) void gn_apply_t(const float* __restrict__ x,
                                                  const float2* __restrict__ AB,
                                                  u16* __restrict__ hnt) {
  int p0 = blockIdx.x * 32, c0 = blockIdx.y * 32, b = blockIdx.z;
  __shared__ float tile[32][33];
  int t = threadIdx.x;
  const float* xb = x + (long)b * 2097152;
#pragma unroll
  for (int j = 0; j < 4; ++j) {
    int lc = (t >> 5) + j * 8, lp = t & 31;
    tile[lc][lp] = xb[(long)(c0 + lc) * 4096 + p0 + lp];
  }
  __syncthreads();
#pragma unroll
  for (int j = 0; j < 4; ++j) {
    int lp = (t >> 5) + j * 8, lc = t & 31;
    float2 ab = AB[b * 512 + c0 + lc];
    float val = tile[lc][lp] * ab.x + ab.y;
    hnt[(long)b * 2097152 + (long)(p0 + lp) * 512 + c0 + lc] = f2bf(val);
  }
}

// ---------------- in-place row softmax on bf16 [8192][4096] ----------------
__global__ __launch_bounds__(256) void softmax_rows(u16* __restrict__ S) {
  u16* p = S + (long)blockIdx.x * 4096;
  const int t = threadIdx.x;
  s8v h0 = ((const s8v*)p)[t * 2];
  s8v h1 = ((const s8v*)p)[t * 2 + 1];
  float v[16];
#pragma unroll
  for (int j = 0; j < 8; ++j) {
    v[j] = bf2f((u16)h0[j]);
    v[8 + j] = bf2f((u16)h1[j]);
  }
  float mx = v[0];
#pragma unroll
  for (int j = 1; j < 16; ++j) mx = fmaxf(mx, v[j]);
#pragma unroll
  for (int o = 32; o; o >>= 1) mx = fmaxf(mx, __shfl_xor(mx, o, 64));
  __shared__ float red[4], red2[4];
  int lane = t & 63, wv = t >> 6;
  if (lane == 0) red[wv] = mx;
  __syncthreads();
  mx = fmaxf(fmaxf(red[0], red[1]), fmaxf(red[2], red[3]));
  float s = 0.f;
#pragma unroll
  for (int j = 0; j < 16; ++j) {
    v[j] = __expf(v[j] - mx);
    s += v[j];
  }
#pragma unroll
  for (int o = 32; o; o >>= 1) s += __shfl_xor(s, o, 64);
  if (lane == 0) red2[wv] = s;
  __syncthreads();
  s = red2[0] + red2[1] + red2[2] + red2[3];
  float inv = 1.0f / s;
  s8v o0, o1;
#pragma unroll
  for (int j = 0; j < 8; ++j) {
    o0[j] = (short)f2bf(v[j] * inv);
    o1[j] = (short)f2bf(v[8 + j] * inv);
  }
  ((s8v*)p)[t * 2] = o0;
  ((s8v*)p)[t * 2 + 1] = o1;
}

// ---------------- split-K reduce: out = p[i] + p[4194304+i] (bf16) ---------
__global__ __launch_bounds__(256) void reduce_pv(const u16* __restrict__ p,
                                                 u16* __restrict__ out) {
  long i = ((long)blockIdx.x * 256 + threadIdx.x) * 8;
  s8v a = *(const s8v*)(p + i);
  s8v b = *(const s8v*)(p + 4194304 + i);
  s8v o;
#pragma unroll
  for (int j = 0; j < 8; ++j)
    o[j] = (short)f2bf(bf2f((u16)a[j]) + bf2f((u16)b[j]));
  *(s8v*)(out + i) = o;
}

// ---------------- fused QKV GEMM: A-tile staged once for 3 weights --------
// BM=128, BN=64, K=512. 3-stage pipeline, fine vmcnt, one barrier/iter.
// q,k -> [p][c] scatter; v -> [c][p] packed (transposed in epilogue).
__global__ __launch_bounds__(256) void gemm_qkv3(
    const u16* __restrict__ hnt, const u16* __restrict__ wqb,
    u16* __restrict__ qt, u16* __restrict__ kt, u16* __restrict__ vt,
    const float* __restrict__ bq, const float* __restrict__ bk,
    const float* __restrict__ bv) {
  constexpr int MI = 4, NI = 2, AGW = 2, NLD = 5;
  __shared__ __align__(16) u16 la[3][4096];
  __shared__ __align__(16) u16 lb[3][3][2048];
  const int t = threadIdx.x;
  const int lane = t & 63, wv = t >> 6;
  const int wm = wv >> 1, wn = wv & 1;

  int lin = blockIdx.x;
  int xcd = lin & 7, s = lin >> 3;
  int bn_i = s % 8, t2 = s / 8;
  int bm_i = (t2 % 4) * 8 + xcd;
  int bb = t2 / 4;
  const int bm = bm_i * 128, bn = bn_i * 64;

  const u16* A = hnt + (long)bb * 2097152;
  const u16* aP[AGW];
#pragma unroll
  for (int j = 0; j < AGW; ++j)
    aP[j] = A + (long)(bm + (wv + j * 4) * 16 + (lane & 15)) * 512 +
            (lane >> 4) * 8;
  const u16* bP[3];
#pragma unroll
  for (int w = 0; w < 3; ++w)
    bP[w] = wqb + (long)w * 262144 +
            (long)(bn + wv * 16 + (lane & 15)) * 512 + (lane >> 4) * 8;

  auto issue = [&](int buf) {
#pragma unroll
    for (int j = 0; j < AGW; ++j) {
      gload16(aP[j], &la[buf][(wv + j * 4) * 512 + lane * 8]);
      aP[j] += 32;
    }
#pragma unroll
    for (int w = 0; w < 3; ++w) {
      gload16(bP[w], &lb[buf][w][wv * 512 + lane * 8]);
      bP[w] += 32;
    }
  };

  f4v acc[3][MI][NI];
#pragma unroll
  for (int w = 0; w < 3; ++w)
#pragma unroll
    for (int i = 0; i < MI; ++i)
#pragma unroll
      for (int j = 0; j < NI; ++j) acc[w][i][j] = (f4v){0.f, 0.f, 0.f, 0.f};

  issue(0);
  issue(1);
  int cur = 0, nxt = 2;
  for (int it = 0; it < 16; ++it) {
    if (it < 15)
      asm volatile("s_waitcnt vmcnt(%0)" ::"n"(NLD) : "memory");
    else
      asm volatile("s_waitcnt vmcnt(0)" ::: "memory");
    asm volatile("s_barrier" ::: "memory");
    if (it + 2 < 16) issue(nxt);

    s8v af[MI], bfr[3][NI];
#pragma unroll
    for (int mi = 0; mi < MI; ++mi)
      af[mi] = *(const s8v*)&la[cur][((wm * MI + mi) * 64 + lane) * 8];
#pragma unroll
    for (int w = 0; w < 3; ++w)
#pragma unroll
      for (int ni = 0; ni < NI; ++ni)
        bfr[w][ni] =
            *(const s8v*)&lb[cur][w][((wn * NI + ni) * 64 + lane) * 8];
#pragma unroll
    for (int w = 0; w < 3; ++w)
#pragma unroll
      for (int mi = 0; mi < MI; ++mi)
#pragma unroll
        for (int ni = 0; ni < NI; ++ni)
          acc[w][mi][ni] = __builtin_amdgcn_mfma_f32_16x16x32_bf16(
              af[mi], bfr[w][ni], acc[w][mi][ni], 0, 0, 0);
    cur = cur == 2 ? 0 : cur + 1;
    nxt = nxt == 2 ? 0 : nxt + 1;
  }

  const int quad = lane >> 4, col = lane & 15;
#pragma unroll
  for (int w = 0; w < 3; ++w) {
    const float* bias = w == 0 ? bq : w == 1 ? bk : bv;
    u16* dst = w == 0 ? qt : kt;
#pragma unroll
    for (int mi = 0; mi < MI; ++mi) {
#pragma unroll
      for (int ni = 0; ni < NI; ++ni) {
        int n = bn + wn * 32 + ni * 16 + col;
        int m0 = bm + wm * 64 + mi * 16 + quad * 4;
        f4v vv = acc[w][mi][ni];
        float bsv = bias[n];
        if (w == 2) {
          ushort4 pk;
          pk.x = f2bf(vv[0] + bsv); pk.y = f2bf(vv[1] + bsv);
          pk.z = f2bf(vv[2] + bsv); pk.w = f2bf(vv[3] + bsv);
          *(ushort4*)&vt[(long)bb * 2097152 + (long)n * 4096 + m0] = pk;
        } else {
#pragma unroll
          for (int r2 = 0; r2 < 4; ++r2)
            dst[(long)bb * 2097152 + (long)(m0 + r2) * 512 + n] =
                f2bf(vv[r2] + bsv);
        }
      }
    }
  }
}

// ---------------- NT GEMM: C[M][N] = A[M][K] * Bt[N][K]^T ----------------
// 3-stage pipeline: fine s_waitcnt vmcnt(NLD) (never 0 mid-loop), one raw
// s_barrier per K-step, loads in flight across the barrier. XCD swizzle.
template <int MODE, int BM, int BN>
__global__ __launch_bounds__(256) void gemm_nt(
    const u16* __restrict__ Ag, long sA, const u16* __restrict__ Btg, long sB,
    void* __restrict__ Cg, long sC, int nx, int nyg, int K, long lda, long ldb,
    int N, const float* __restrict__ b0, const float* __restrict__ resid,
    long sR, float scale) {
  constexpr int MI = BM / 32, NI = BN / 32;
  constexpr int AGW = BM / 64, BGW = BN / 64;
  constexpr int NLD = AGW + BGW;
  __shared__ __align__(16) u16 lds_a[3][BM * 32];
  __shared__ __align__(16) u16 lds_b[3][BN * 32];
  const int t = threadIdx.x;
  const int lane = t & 63, wv = t >> 6;
  const int wm = wv >> 1, wn = wv & 1;

  int lin = blockIdx.x;
  int xcd = lin & 7, s = lin >> 3;
  int bn_i = s % nx, t2 = s / nx;
  int bm_i = (t2 % nyg) * 8 + xcd;
  int bz = t2 / nyg;

  const u16* A = Ag;
  const u16* Bt = Btg;
  long c_off = 0;
  if constexpr (MODE == MODE_PV) {
    int ks = bz >> 1, bb = bz & 1;
    A += (long)bb * sA + (long)ks * 2048;
    Bt += (long)bb * sB + (long)ks * 2048;
    c_off = (long)ks * 4194304 + (long)bb * sC;
  } else {
    A += (long)bz * sA;
    Bt += (long)bz * sB;
    c_off = (long)bz * sC;
  }
  const int bm = bm_i * BM, bn = bn_i * BN;

  const u16* aP[AGW];
  const u16* bP[BGW];
#pragma unroll
  for (int j = 0; j < AGW; ++j)
    aP[j] = A + (long)(bm + (wv + j * 4) * 16 + (lane & 15)) * lda +
            (lane >> 4) * 8;
#pragma unroll
  for (int j = 0; j < BGW; ++j)
    bP[j] = Bt + (long)(bn + (wv + j * 4) * 16 + (lane & 15)) * ldb +
            (lane >> 4) * 8;

  auto issue = [&](int buf) {
#pragma unroll
    for (int j = 0; j < AGW; ++j) {
      gload16(aP[j], &lds_a[buf][(wv + j * 4) * 512 + lane * 8]);
      aP[j] += 32;
    }
#pragma unroll
    for (int j = 0; j < BGW; ++j) {
      gload16(bP[j], &lds_b[buf][(wv + j * 4) * 512 + lane * 8]);
      bP[j] += 32;
    }
  };

  f4v acc[MI][NI];
#pragma unroll
  for (int i = 0; i < MI; ++i)
#pragma unroll
    for (int j = 0; j < NI; ++j) acc[i][j] = (f4v){0.f, 0.f, 0.f, 0.f};

  const int NIT = K / 32;
  issue(0);
  if (NIT > 1) issue(1);

  int cur = 0, nxt = 2;
  for (int it = 0; it < NIT; ++it) {
    if (it < NIT - 1)
      asm volatile("s_waitcnt vmcnt(%0)" ::"n"(NLD) : "memory");
    else
      asm volatile("s_waitcnt vmcnt(0)" ::: "memory");
    asm volatile("s_barrier" ::: "memory");
    if (it + 2 < NIT) issue(nxt);

    s8v af[MI], bfr[NI];
#pragma unroll
    for (int mi = 0; mi < MI; ++mi)
      af[mi] = *(const s8v*)&lds_a[cur][((wm * MI + mi) * 64 + lane) * 8];
#pragma unroll
    for (int ni = 0; ni < NI; ++ni)
      bfr[ni] = *(const s8v*)&lds_b[cur][((wn * NI + ni) * 64 + lane) * 8];
#pragma unroll
    for (int mi = 0; mi < MI; ++mi)
#pragma unroll
      for (int ni = 0; ni < NI; ++ni)
        acc[mi][ni] = __builtin_amdgcn_mfma_f32_16x16x32_bf16(
            af[mi], bfr[ni], acc[mi][ni], 0, 0, 0);
    cur = cur == 2 ? 0 : cur + 1;
    nxt = nxt == 2 ? 0 : nxt + 1;
  }

  const int quad = lane >> 4, col = lane & 15;
#pragma unroll
  for (int mi = 0; mi < MI; ++mi) {
#pragma unroll
    for (int ni = 0; ni < NI; ++ni) {
      int n = bn + wn * (BN / 2) + ni * 16 + col;
      int m0 = bm + wm * (BM / 2) + mi * 16 + quad * 4;
      f4v vv = acc[mi][ni];
#pragma unroll
      for (int r2 = 0; r2 < 4; ++r2) {
        int m = m0 + r2;
        float val = vv[r2];
        if constexpr (MODE == MODE_SCALE) val *= scale;
        if constexpr (MODE == MODE_FINAL) {
          val += b0[m] + resid[(long)bz * sR + (long)m * N + n];
          ((float*)Cg)[c_off + (long)m * N + n] = val;
        } else {
          ((u16*)Cg)[c_off + (long)m * N + n] = f2bf(val);
        }
      }
    }
  }
  (void)scale; (void)resid;
}

extern "C" void kernel_launch(void* const* d_in, const int* in_sizes, int n_in,
                              void* d_out, int out_size, void* d_ws,
                              size_t ws_size, hipStream_t stream) {
  const float* x = (const float*)d_in[0];
  const float* gamma = (const float*)d_in[1];
  const float* beta = (const float*)d_in[2];
  const float* wq = (const float*)d_in[3];
  const float* bq = (const float*)d_in[4];
  const float* wk = (const float*)d_in[5];
  const float* bk = (const float*)d_in[6];
  const float* wv = (const float*)d_in[7];
  const float* bv = (const float*)d_in[8];
  const float* wo = (const float*)d_in[9];
  const float* bo = (const float*)d_in[10];

  u16* ws = (u16*)d_ws;
  u16* hnt = ws;            // [2][4096][512]; after QKV free; reduce -> out_t
  u16* qt = ws + 4194304;   // q_t; during PV: split-K partial ks=0
  u16* kt = ws + 8388608;   // k_t; during PV: split-K partial ks=1
  u16* vt = ws + 12582912;  // v [2][512][4096] (written transposed by QKV)
  u16* S = ws + 16777216;   // [2][4096][4096] bf16
  u16* wqb = ws + 50331648; // 4 weights bf16
  u16* wob = ws + 51118080;
  float2* part = (float2*)((char*)d_ws + 102760448);
  float2* AB = (float2*)((char*)d_ws + 102764544);

  w2bf<<<dim3(256, 4), 256, 0, stream>>>(wq, wk, wv, wo, wqb);
  gn_stats<<<512, 256, 0, stream>>>(x, part);
  gn_ab<<<4, 256, 0, stream>>>(part, gamma, beta, AB);
  gn_apply_t<<<dim3(128, 16, 2), 256, 0, stream>>>(x, AB, hnt);

  // fused q/k/v: 8(xcd)x8(bn)x4(bm-grp)x2(b) = 512 blocks
  gemm_qkv3<<<512, 256, 0, stream>>>(hnt, wqb, qt, kt, vt, bq, bk, bv);

  // S = scale * q_t k_t^T: nx=32, nyg=4, nz=2 -> 2048 blocks
  gemm_nt<MODE_SCALE, 128, 128><<<2048, 256, 0, stream>>>(
      qt, 2097152, kt, 2097152, S, 16777216L, 32, 4, 512, 512, 512, 4096,
      nullptr, nullptr, 0, 0.044194173824159216f);

  softmax_rows<<<8192, 256, 0, stream>>>(S);

  // PV split-K=2, 128x128 tiles: nx=4, nyg=4, nz=4 -> 512 blocks
  gemm_nt<MODE_PV, 128, 128><<<512, 256, 0, stream>>>(
      S, 16777216L, vt, 2097152, qt, 2097152, 4, 4, 2048, 4096, 4096, 512,
      nullptr, nullptr, 0, 0.f);

  // out_t = partial0 + partial1 -> hnt slot
  reduce_pv<<<2048, 256, 0, stream>>>(qt, hnt);

  // d_out = wo . out_t^T + bo + x: 64x128, nx=32, nyg=1, nz=2 -> 512 blocks
  gemm_nt<MODE_FINAL, 64, 128><<<512, 256, 0, stream>>>(
      wob, 0, hnt, 2097152, d_out, 2097152, 32, 1, 512, 512, 512, 4096, bo,
      x, 2097152, 0.f);

  (void)in_sizes; (void)n_in; (void)out_size; (void)ws_size;
}